// Round 1
// baseline (2571.453 us; speedup 1.0000x reference)
//
#include <hip/hip_runtime.h>

typedef unsigned int uint;
typedef unsigned short ushort;
typedef __attribute__((ext_vector_type(8))) short short8;
typedef __attribute__((ext_vector_type(4))) float f32x4;

#define T_STEPS 128
#define NGRP 128

__device__ __forceinline__ ushort f2bf(float f) {
  union { float f; uint u; } v; v.f = f;
  uint r = v.u + 0x7fffu + ((v.u >> 16) & 1u);  // RNE
  return (ushort)(r >> 16);
}
__device__ __forceinline__ float bf2f(ushort u) {
  union { uint u; float f; } v; v.u = ((uint)u) << 16;
  return v.f;
}

union F8 { uint2 u2[2]; short8 s; };

// ---------------- init kernels ----------------

// xs f32 [64][128][512] -> bf16
__global__ void convert_xs_kernel(const float* __restrict__ xs, ushort* __restrict__ xb) {
  int i = (blockIdx.x * 256 + threadIdx.x) * 8;
  float4 a = *(const float4*)(xs + i);
  float4 c = *(const float4*)(xs + i + 4);
  union { ushort r[8]; uint4 v; } p;
  p.r[0] = f2bf(a.x); p.r[1] = f2bf(a.y); p.r[2] = f2bf(a.z); p.r[3] = f2bf(a.w);
  p.r[4] = f2bf(c.x); p.r[5] = f2bf(c.y); p.r[6] = f2bf(c.z); p.r[7] = f2bf(c.w);
  *(uint4*)(xb + i) = p.v;
}

// W f32 [K][4096] -> WT bf16 [4096][1536] at k-offset ko (W_ih: ko=0, W_hh: ko=512)
__global__ void transpose_w_kernel(const float* __restrict__ W, ushort* __restrict__ WT, int ko) {
  __shared__ ushort tile[32][33];
  int kt = blockIdx.x * 32, nt = blockIdx.y * 32;
  int tx = threadIdx.x & 31, ty = threadIdx.x >> 5;
#pragma unroll
  for (int i = 0; i < 4; ++i) {
    int kk = ty + i * 8;
    tile[kk][tx] = f2bf(W[(kt + kk) * 4096 + nt + tx]);
  }
  __syncthreads();
#pragma unroll
  for (int i = 0; i < 4; ++i) {
    int nn = ty + i * 8;
    WT[(nt + nn) * 1536 + ko + kt + tx] = tile[tx][nn];
  }
}

// ---------------- persistent LSTM kernel ----------------

__device__ __forceinline__ void load_chunk(uint4* st, const ushort* __restrict__ xsb,
                                           const ushort* __restrict__ hrd,
                                           int t, int nc, int r0, int col8) {
  if (nc < 4) {  // x part: xs[b][t][nc*128 ..]
#pragma unroll
    for (int i = 0; i < 4; ++i)
      st[i] = *(const uint4*)(xsb + ((r0 + 16 * i) * 128 + t) * 512 + nc * 128 + col8);
  } else {       // h part: h[b][(nc-4)*128 ..]
#pragma unroll
    for (int i = 0; i < 4; ++i)
      st[i] = *(const uint4*)(hrd + (r0 + 16 * i) * 1024 + (nc - 4) * 128 + col8);
  }
}

__device__ __forceinline__ void store_chunk(const uint4* st, char* dst, int sdst0) {
#pragma unroll
  for (int i = 0; i < 4; ++i)
    *(uint4*)(dst + sdst0 + i * 4096) = st[i];
}

__device__ __forceinline__ void compute_chunk(const char* Ab, const char* Wrow,
                                              const int (&offA)[4][2], const int (&offB)[2][4][2],
                                              f32x4& acc0, f32x4& acc1) {
#pragma unroll
  for (int ks = 0; ks < 4; ++ks) {
    F8 a, b0, b1;
    a.u2[0]  = *(const uint2*)(Ab + offA[ks][0]);
    a.u2[1]  = *(const uint2*)(Ab + offA[ks][1]);
    b0.u2[0] = *(const uint2*)(Wrow + offB[0][ks][0]);
    b0.u2[1] = *(const uint2*)(Wrow + offB[0][ks][1]);
    b1.u2[0] = *(const uint2*)(Wrow + offB[1][ks][0]);
    b1.u2[1] = *(const uint2*)(Wrow + offB[1][ks][1]);
    acc0 = __builtin_amdgcn_mfma_f32_16x16x32_bf16(a.s, b0.s, acc0, 0, 0, 0);
    acc1 = __builtin_amdgcn_mfma_f32_16x16x32_bf16(a.s, b1.s, acc1, 0, 0, 0);
  }
}

__global__ __launch_bounds__(256, 1) void lstm_persist(
    const ushort* __restrict__ xsb, const ushort* __restrict__ WT,
    const float* __restrict__ bias, const float* __restrict__ Wo,
    const float* __restrict__ bo, ushort* __restrict__ hbuf,
    uint* __restrict__ cnt, float* __restrict__ out) {

  // LDS: W tile 96KB (rows n=0..31, 1536 bf16 each, XOR-swizzled) + A double buffer 32KB
  __shared__ ushort sW[32 * 1536];
  __shared__ ushort sA[2][64 * 128];

  const int tid = threadIdx.x;
  const int wg = blockIdx.x;
  const int lane = tid & 63;
  const int wv = tid >> 6;        // wave id: M-tile (rows 16*wv..)
  const int c16 = lane & 15;
  const int kg = lane >> 4;       // 0..3
  const int u = lane & 3;

  // ---- stage W tile into LDS (once). row n -> gate col gcol(n) of [W_ih|W_hh] ----
  for (int idx = tid; idx < 32 * 192; idx += 256) {
    int n = idx / 192, g = idx - n * 192;  // g: 16B granule within 3072B row
    int gcol = ((n & 15) >> 2) * 1024 + wg * 8 + ((n >> 4) << 2) + (n & 3);
    uint4 v = *(const uint4*)(WT + gcol * 1536 + g * 8);
    int db = n * 3072 + ((g * 16) ^ ((n & 7) << 4));
    *(uint4*)((char*)sW + db) = v;
  }

  // bias per lane (col c16 of each of the two N-fragments)
  const int gate = c16 >> 2;
  const float bias0 = bias[gate * 1024 + wg * 8 + 0 + u];
  const float bias1 = bias[gate * 1024 + wg * 8 + 4 + u];

  // precomputed swizzled LDS byte offsets (chunk-invariant)
  int offA[4][2], offB[2][4][2];
  {
    int arow = wv * 16 + c16;
    int swA = (arow & 7) << 4;
#pragma unroll
    for (int ks = 0; ks < 4; ++ks)
#pragma unroll
      for (int hf = 0; hf < 2; ++hf)
        offA[ks][hf] = arow * 256 + ((ks * 64 + hf * 32 + kg * 8) ^ swA);
#pragma unroll
    for (int nf = 0; nf < 2; ++nf) {
      int n = nf * 16 + c16;
      int swB = (n & 7) << 4;
#pragma unroll
      for (int ks = 0; ks < 4; ++ks)
#pragma unroll
        for (int hf = 0; hf < 2; ++hf)
          offB[nf][ks][hf] = n * 3072 + ((ks * 64 + hf * 32 + kg * 8) ^ swB);
    }
  }

  // staging constants: thread handles granules (r0+16i, col gb) of the [64][128] chunk
  const int r0 = tid >> 4;
  const int gb = tid & 15;
  const int col8 = gb * 8;
  const int sdst0 = r0 * 256 + ((gb * 16) ^ ((r0 & 7) << 4));

  float cst[8];  // c-state [nf*4+r], valid on lanes with c16<4
#pragma unroll
  for (int i = 0; i < 8; ++i) cst[i] = 0.f;

  __syncthreads();  // sW ready

  for (int t = 0; t < T_STEPS; ++t) {
    const ushort* hrd = hbuf + (t & 1) * 65536;
    ushort* hwr = hbuf + ((t + 1) & 1) * 65536;
    f32x4 acc0 = {bias0, bias0, bias0, bias0};
    f32x4 acc1 = {bias1, bias1, bias1, bias1};
    uint4 stA[4], stB[4];

    // prologue: chunks 0,1 (both x-part, no sync dependence)
    load_chunk(stA, xsb, hrd, t, 0, r0, col8);
    load_chunk(stB, xsb, hrd, t, 1, r0, col8);
    store_chunk(stA, (char*)sA[0], sdst0);
    __syncthreads();

    for (int chp = 0; chp < 12; chp += 2) {
      // ---- even chunk chp ----
      if (chp == 2 && t > 0) {
        // deferred barrier wait: needed before first h-chunk load (chunk 4 at chp==2)
        if (tid == 0) {
          uint tgt = (uint)(NGRP * t);
          while (__hip_atomic_load(cnt, __ATOMIC_RELAXED, __HIP_MEMORY_SCOPE_AGENT) < tgt)
            __builtin_amdgcn_s_sleep(2);
          (void)__hip_atomic_load(cnt, __ATOMIC_ACQUIRE, __HIP_MEMORY_SCOPE_AGENT);
        }
        __syncthreads();
      }
      if (chp + 2 < 12) load_chunk(stA, xsb, hrd, t, chp + 2, r0, col8);
      compute_chunk((const char*)sA[0], (const char*)sW + chp * 256, offA, offB, acc0, acc1);
      store_chunk(stB, (char*)sA[1], sdst0);  // chunk chp+1 (always exists)
      __syncthreads();
      // ---- odd chunk chp+1 ----
      if (chp + 3 < 12) load_chunk(stB, xsb, hrd, t, chp + 3, r0, col8);
      compute_chunk((const char*)sA[1], (const char*)sW + (chp + 1) * 256, offA, offB, acc0, acc1);
      if (chp + 2 < 12) store_chunk(stA, (char*)sA[0], sdst0);
      __syncthreads();
    }

    // ---- gates & state update (cols interleaved [i0..3 f0..3 g0..3 o0..3] per frag) ----
#pragma unroll
    for (int nf = 0; nf < 2; ++nf) {
      f32x4 acc = nf ? acc1 : acc0;
#pragma unroll
      for (int r = 0; r < 4; ++r) {
        float own = acc[r];
        float vf = __shfl_xor(own, 4);
        float vg = __shfl_xor(own, 8);
        float vo = __shfl_xor(own, 12);
        if (c16 < 4) {
          float ig = 1.f / (1.f + expf(-own));
          float fg = 1.f / (1.f + expf(-vf));
          float gg = fmaxf(vg, 0.f);
          float og = 1.f / (1.f + expf(-vo));
          float cn = fg * cst[nf * 4 + r] + ig * gg;
          cst[nf * 4 + r] = cn;
          int row = wv * 16 + kg * 4 + r;
          int j = wg * 8 + nf * 4 + u;
          hwr[row * 1024 + j] = f2bf(og * fmaxf(cn, 0.f));
        }
      }
    }
    __syncthreads();  // drain h stores of all threads before release
    if (tid == 0)
      __hip_atomic_fetch_add(cnt, 1u, __ATOMIC_RELEASE, __HIP_MEMORY_SCOPE_AGENT);
  }

  // ---- wait for all final h, then output GEMM: out = h_T @ W_o + b_o (f32 VALU) ----
  if (tid == 0) {
    uint tgt = (uint)(NGRP * T_STEPS);
    while (__hip_atomic_load(cnt, __ATOMIC_RELAXED, __HIP_MEMORY_SCOPE_AGENT) < tgt)
      __builtin_amdgcn_s_sleep(2);
    (void)__hip_atomic_load(cnt, __ATOMIC_ACQUIRE, __HIP_MEMORY_SCOPE_AGENT);
  }
  __syncthreads();
  {
    int oidx = wg * 256 + tid;           // 0..32767
    int bb = oidx >> 9, oc = oidx & 511;
    const ushort* hr = hbuf + bb * 1024; // final h lives in buffer 0 (T even)
    float s = bo[oc];
#pragma unroll 8
    for (int k = 0; k < 1024; ++k)
      s = fmaf(bf2f(hr[k]), Wo[k * 512 + oc], s);
    out[oidx] = s;
  }
}

// ---------------- host launch ----------------

extern "C" void kernel_launch(void* const* d_in, const int* in_sizes, int n_in,
                              void* d_out, int out_size, void* d_ws, size_t ws_size,
                              hipStream_t stream) {
  (void)in_sizes; (void)n_in; (void)out_size; (void)ws_size;
  const float* xs  = (const float*)d_in[0];
  const float* Wih = (const float*)d_in[1];
  const float* Whh = (const float*)d_in[2];
  const float* b   = (const float*)d_in[3];
  const float* Wo  = (const float*)d_in[4];
  const float* bo  = (const float*)d_in[5];
  float* out = (float*)d_out;

  char* ws = (char*)d_ws;
  uint* cnt    = (uint*)ws;                                   // barrier counter
  ushort* hbuf = (ushort*)(ws + 1024);                        // 2 x [64][1024] bf16
  ushort* xsb  = (ushort*)(ws + 1024 + 262144);               // [64][128][512] bf16
  ushort* WT   = (ushort*)(ws + 1024 + 262144 + 8388608);     // [4096][1536] bf16

  // reset barrier counter + zero both h buffers (h0 = 0) every call (graph-safe)
  hipMemsetAsync(ws, 0, 1024 + 262144, stream);
  convert_xs_kernel<<<2048, 256, 0, stream>>>(xs, xsb);
  transpose_w_kernel<<<dim3(16, 128), 256, 0, stream>>>(Wih, WT, 0);
  transpose_w_kernel<<<dim3(32, 128), 256, 0, stream>>>(Whh, WT, 512);
  lstm_persist<<<NGRP, 256, 0, stream>>>(xsb, WT, b, Wo, bo, hbuf, cnt, out);
}

// Round 2
// 1430.658 us; speedup vs baseline: 1.7974x; 1.7974x over previous
//
#include <hip/hip_runtime.h>

typedef unsigned int uint;
typedef unsigned short ushort;
typedef __attribute__((ext_vector_type(8))) short short8;
typedef __attribute__((ext_vector_type(4))) float f32x4;
typedef __attribute__((ext_vector_type(2))) uint uintx2;

#define T_STEPS 128
#define NGRP 256
#define NCNT 8            // stripe counters, 128B apart
#define CPW (NGRP/NCNT)   // adds per counter per step

__device__ __forceinline__ ushort f2bf(float f) {
  union { float f; uint u; } v; v.f = f;
  uint r = v.u + 0x7fffu + ((v.u >> 16) & 1u);  // RNE
  return (ushort)(r >> 16);
}
__device__ __forceinline__ float bf2f(ushort u) {
  union { uint u; float f; } v; v.u = ((uint)u) << 16;
  return v.f;
}

union F8 { uint4 u4; short8 s; };

// ---------------- init kernels ----------------

// xs f32 [64][128][512] -> bf16
__global__ void convert_xs_kernel(const float* __restrict__ xs, ushort* __restrict__ xb) {
  int i = (blockIdx.x * 256 + threadIdx.x) * 8;
  float4 a = *(const float4*)(xs + i);
  float4 c = *(const float4*)(xs + i + 4);
  union { ushort r[8]; uint4 v; } p;
  p.r[0] = f2bf(a.x); p.r[1] = f2bf(a.y); p.r[2] = f2bf(a.z); p.r[3] = f2bf(a.w);
  p.r[4] = f2bf(c.x); p.r[5] = f2bf(c.y); p.r[6] = f2bf(c.z); p.r[7] = f2bf(c.w);
  *(uint4*)(xb + i) = p.v;
}

// W f32 [K][4096] -> WT bf16 [4096][1536] at k-offset ko (W_ih: ko=0, W_hh: ko=512)
__global__ void transpose_w_kernel(const float* __restrict__ W, ushort* __restrict__ WT, int ko) {
  __shared__ ushort tile[32][33];
  int kt = blockIdx.x * 32, nt = blockIdx.y * 32;
  int tx = threadIdx.x & 31, ty = threadIdx.x >> 5;
#pragma unroll
  for (int i = 0; i < 4; ++i) {
    int kk = ty + i * 8;
    tile[kk][tx] = f2bf(W[(kt + kk) * 4096 + nt + tx]);
  }
  __syncthreads();
#pragma unroll
  for (int i = 0; i < 4; ++i) {
    int nn = ty + i * 8;
    WT[(nt + nn) * 1536 + ko + kt + tx] = tile[tx][nn];
  }
}

// ---------------- persistent LSTM kernel ----------------
// 256 WGs, 1/CU (112KB LDS). WG owns 4 hidden units (16 gate cols).
// A tile [64 rows x 1536 k] per step, staged in 6 chunks of [64 x 256].
// chunks 0,1 = x contribution (no barrier dep), 2..5 = h contribution.

__device__ __forceinline__ void load_chunk(uint4* R, const ushort* __restrict__ xsb,
                                           const ushort* __restrict__ hrd,
                                           int t, int c, int r0, int gb) {
  if (c < 2) {  // xs[b][t][c*256 + ...]
    const ushort* p = xsb + t * 512 + c * 256 + gb * 8;
#pragma unroll
    for (int i = 0; i < 4; ++i) {
      const ushort* q = p + (r0 + 16 * i) * 65536;
      R[2 * i]     = *(const uint4*)(q);
      R[2 * i + 1] = *(const uint4*)(q + 128);
    }
  } else {      // h[b][(c-2)*256 + ...]
    const ushort* p = hrd + (c - 2) * 256 + gb * 8;
#pragma unroll
    for (int i = 0; i < 4; ++i) {
      const ushort* q = p + (r0 + 16 * i) * 1024;
      R[2 * i]     = *(const uint4*)(q);
      R[2 * i + 1] = *(const uint4*)(q + 128);
    }
  }
}

__device__ __forceinline__ void store_chunk(const uint4* R, char* dst, int sd0) {
#pragma unroll
  for (int i = 0; i < 4; ++i) {
    *(uint4*)(dst + sd0 + i * 8192)       = R[2 * i];
    *(uint4*)(dst + sd0 + i * 8192 + 256) = R[2 * i + 1];
  }
}

__device__ __forceinline__ void compute_chunk(const char* Ab, const char* Wb,
                                              const int (&offA)[8], const int (&offB)[8],
                                              f32x4& acc) {
#pragma unroll
  for (int ks = 0; ks < 8; ++ks) {
    F8 a, b;
    a.u4 = *(const uint4*)(Ab + offA[ks]);
    b.u4 = *(const uint4*)(Wb + offB[ks]);
    acc = __builtin_amdgcn_mfma_f32_16x16x32_bf16(a.s, b.s, acc, 0, 0, 0);
  }
}

__global__ __launch_bounds__(256, 1) void lstm_persist(
    const ushort* __restrict__ xsb, const ushort* __restrict__ WT,
    const float* __restrict__ bias, const float* __restrict__ Wo,
    const float* __restrict__ bo, ushort* __restrict__ hbuf,
    uint* __restrict__ cnt, float* __restrict__ out) {

  __shared__ ushort sW[16 * 1536];    // 48KB: 16 gate-cols x 1536 k, XOR-swizzled
  __shared__ ushort sA[2][64 * 256];  // 64KB: A chunk double buffer

  const int tid = threadIdx.x;
  const int wg = blockIdx.x;
  const int lane = tid & 63;
  const int wv = tid >> 6;        // wave id -> M rows [16wv, 16wv+16)
  const int c16 = lane & 15;
  const int kg = lane >> 4;       // k-group 0..3

  // ---- stage W tile into LDS (once). sW row n <-> gate col gcol(n) ----
  for (int idx = tid; idx < 16 * 192; idx += 256) {
    int n = idx / 192, g = idx - n * 192;   // g: 16B granule in 3072B row
    int gcol = (n >> 2) * 1024 + wg * 4 + (n & 3);
    uint4 v = *(const uint4*)(WT + gcol * 1536 + g * 8);
    int db = n * 3072 + ((g * 16) ^ ((n & 7) << 4));
    *(uint4*)((char*)sW + db) = v;
  }

  const int gate = c16 >> 2;
  const int u = c16 & 3;
  const float bias0 = bias[gate * 1024 + wg * 4 + u];

  // conflict-free swizzled LDS byte offsets (16B fragment reads)
  int offA[8], offB[8];
  {
    int arow = wv * 16 + c16;
    int swA = (arow & 7) << 4;
    int swB = (c16 & 7) << 4;
#pragma unroll
    for (int ks = 0; ks < 8; ++ks) {
      int ko = ks * 64 + kg * 16;
      offA[ks] = arow * 512 + (ko ^ swA);
      offB[ks] = c16 * 3072 + (ko ^ swB);
    }
  }

  // staging: thread -> rows r0+16i, 16B granules gb and gb+16 of [64][256] chunk
  const int r0 = tid >> 4;
  const int gb = tid & 15;
  const int sd0 = r0 * 512 + ((gb * 16) ^ ((r0 & 7) << 4));

  float cst[4] = {0.f, 0.f, 0.f, 0.f};  // c-state (lanes c16<4 meaningful)

  __syncthreads();  // sW ready

  for (int t = 0; t < T_STEPS; ++t) {
    const ushort* __restrict__ hrd = hbuf + t * 65536;        // h_t (unique addr)
    ushort* __restrict__ hwr = hbuf + (t + 1) * 65536;        // h_{t+1}
    f32x4 acc = {bias0, bias0, bias0, bias0};
    uint4 R0[8], R1[8];

    // prologue: x chunks 0,1 (no barrier dependence)
    load_chunk(R0, xsb, hrd, t, 0, r0, gb);
    load_chunk(R1, xsb, hrd, t, 1, r0, gb);
    store_chunk(R0, (char*)sA[0], sd0);
    __syncthreads();

#pragma unroll
    for (int c = 0; c < 6; ++c) {
      compute_chunk((const char*)sA[c & 1], (const char*)sW + c * 512, offA, offB, acc);
      if (c == 0) {
        // spin (overlapped with chunk-0 compute issue) before first h load
        if (t > 0 && tid < NCNT) {
          uint tgt = (uint)(CPW * t);
          while (__hip_atomic_load(cnt + tid * 32, __ATOMIC_RELAXED,
                                   __HIP_MEMORY_SCOPE_AGENT) < tgt)
            __builtin_amdgcn_s_sleep(1);
        }
        __syncthreads();  // h_t published for ALL threads; fresh addresses -> no inv needed
      }
      if (c + 2 < 6) load_chunk((c & 1) ? R1 : R0, xsb, hrd, t, c + 2, r0, gb);
      if (c + 1 < 6) store_chunk((c & 1) ? R0 : R1, (char*)sA[(c + 1) & 1], sd0);
      __syncthreads();
    }

    // ---- gates & state update (cols [i0..3 f0..3 g0..3 o0..3]) ----
#pragma unroll
    for (int r = 0; r < 4; ++r) {
      float own = acc[r];
      float vf = __shfl_xor(own, 4);
      float vg = __shfl_xor(own, 8);
      float vo = __shfl_xor(own, 12);
      float ig = 1.f / (1.f + __expf(-own));
      float fg = 1.f / (1.f + __expf(-vf));
      float gg = fmaxf(vg, 0.f);
      float og = 1.f / (1.f + __expf(-vo));
      float cn = fg * cst[r] + ig * gg;
      cst[r] = cn;
      int hv = (int)f2bf(og * fmaxf(cn, 0.f));
      int w0 = __shfl_xor(hv, 1);
      uint q0 = (uint)(ushort)hv | ((uint)(ushort)w0 << 16);
      uint q1 = (uint)__shfl_xor((int)q0, 2);
      if (c16 == 0) {  // one 8B write-through store per row: units wg*4..wg*4+3
        uintx2 qv; qv.x = q0; qv.y = q1;
        int row = wv * 16 + kg * 4 + r;
        asm volatile("global_store_dwordx2 %0, %1, off sc0 sc1"
                     :: "v"(hwr + row * 1024 + wg * 4), "v"(qv) : "memory");
      }
    }
    asm volatile("s_waitcnt vmcnt(0)" ::: "memory");  // h at coherence point
    __syncthreads();                                  // all threads' stores drained
    if (tid == 0)
      __hip_atomic_fetch_add(cnt + (wg & 7) * 32, 1u, __ATOMIC_RELAXED,
                             __HIP_MEMORY_SCOPE_AGENT);
  }

  // ---- wait for final h, then out = h_T @ W_o + b_o ----
  if (tid < NCNT) {
    uint tgt = (uint)(CPW * T_STEPS);
    while (__hip_atomic_load(cnt + tid * 32, __ATOMIC_RELAXED,
                             __HIP_MEMORY_SCOPE_AGENT) < tgt)
      __builtin_amdgcn_s_sleep(1);
  }
  __syncthreads();
  if (tid < 128) {
    int oidx = wg * 128 + tid;            // 0..32767
    int bb = oidx >> 9, oc = oidx & 511;
    const ushort* hr = hbuf + T_STEPS * 65536 + bb * 1024;
    float s = bo[oc];
#pragma unroll 8
    for (int k = 0; k < 1024; ++k)
      s = fmaf(bf2f(hr[k]), Wo[k * 512 + oc], s);
    out[oidx] = s;
  }
}

// ---------------- host launch ----------------

extern "C" void kernel_launch(void* const* d_in, const int* in_sizes, int n_in,
                              void* d_out, int out_size, void* d_ws, size_t ws_size,
                              hipStream_t stream) {
  (void)in_sizes; (void)n_in; (void)out_size; (void)ws_size;
  const float* xs  = (const float*)d_in[0];
  const float* Wih = (const float*)d_in[1];
  const float* Whh = (const float*)d_in[2];
  const float* b   = (const float*)d_in[3];
  const float* Wo  = (const float*)d_in[4];
  const float* bo  = (const float*)d_in[5];
  float* out = (float*)d_out;

  char* ws = (char*)d_ws;
  uint* cnt    = (uint*)ws;                               // 8 stripe counters, 128B apart
  ushort* hbuf = (ushort*)(ws + 1024);                    // 129 x [64][1024] bf16 (per-step)
  ushort* xsb  = (ushort*)(ws + 1024 + 16908288);         // [64][128][512] bf16
  ushort* WT   = (ushort*)(ws + 1024 + 16908288 + 8388608); // [4096][1536] bf16

  // zero counters + h_0 every call (graph-safe)
  hipMemsetAsync(ws, 0, 1024 + 131072, stream);
  convert_xs_kernel<<<2048, 256, 0, stream>>>(xs, xsb);
  transpose_w_kernel<<<dim3(16, 128), 256, 0, stream>>>(Wih, WT, 0);
  transpose_w_kernel<<<dim3(32, 128), 256, 0, stream>>>(Whh, WT, 512);
  lstm_persist<<<NGRP, 256, 0, stream>>>(xsb, WT, b, Wo, bo, hbuf, cnt, out);
}

// Round 3
// 1256.976 us; speedup vs baseline: 2.0457x; 1.1382x over previous
//
#include <hip/hip_runtime.h>

typedef unsigned int uint;
typedef unsigned short ushort;
typedef __attribute__((ext_vector_type(8))) short short8;
typedef __attribute__((ext_vector_type(4))) float f32x4;
typedef __attribute__((ext_vector_type(16))) float f32x16;

#define T_STEPS 128
#define NGRP 128
#define NCNT 8            // stripe counters, 128B apart
#define CPW (NGRP/NCNT)   // adds per counter per step = 16

__device__ __forceinline__ ushort f2bf(float f) {
  union { float f; uint u; } v; v.f = f;
  uint r = v.u + 0x7fffu + ((v.u >> 16) & 1u);  // RNE
  return (ushort)(r >> 16);
}
__device__ __forceinline__ float bf2f(ushort u) {
  union { uint u; float f; } v; v.u = ((uint)u) << 16;
  return v.f;
}

union F8 { uint4 u4; short8 s; };

// ---------------- init kernels ----------------

// xs f32 [64][128][512] -> xb bf16 [128][64][512] (t-major)
__global__ void convert_xs_kernel(const float* __restrict__ xs, ushort* __restrict__ xb) {
  int t = blockIdx.x >> 4;
  int b0 = (blockIdx.x & 15) << 2;
  int r = threadIdx.x >> 6;          // 0..3
  int i = (threadIdx.x & 63) * 8;
  const float* src = xs + (((b0 + r) * 128) + t) * 512 + i;
  float4 a = *(const float4*)src;
  float4 c = *(const float4*)(src + 4);
  union { ushort r[8]; uint4 v; } p;
  p.r[0] = f2bf(a.x); p.r[1] = f2bf(a.y); p.r[2] = f2bf(a.z); p.r[3] = f2bf(a.w);
  p.r[4] = f2bf(c.x); p.r[5] = f2bf(c.y); p.r[6] = f2bf(c.z); p.r[7] = f2bf(c.w);
  *(uint4*)(xb + ((t * 64) + b0 + r) * 512 + i) = p.v;
}

// W f32 [K][4096] -> WT bf16 [4096][1536] at k-offset ko (W_ih: ko=0, W_hh: ko=512)
__global__ void transpose_w_kernel(const float* __restrict__ W, ushort* __restrict__ WT, int ko) {
  __shared__ ushort tile[32][33];
  int kt = blockIdx.x * 32, nt = blockIdx.y * 32;
  int tx = threadIdx.x & 31, ty = threadIdx.x >> 5;
#pragma unroll
  for (int i = 0; i < 4; ++i) {
    int kk = ty + i * 8;
    tile[kk][tx] = f2bf(W[(kt + kk) * 4096 + nt + tx]);
  }
  __syncthreads();
#pragma unroll
  for (int i = 0; i < 4; ++i) {
    int nn = ty + i * 8;
    WT[(nt + nn) * 1536 + ko + kt + tx] = tile[tx][nn];
  }
}

// ---------------- persistent LSTM kernel ----------------
// 128 WGs x 4 waves. WG owns 8 hidden units = 32 gate cols (i,f,g,o x 8).
// Weights in VGPRs (24 kfrags/lane). Wave wv owns K-slice:
//   x: [wv*128, wv*128+128)  of k<512 ;  h: [wv*256, wv*256+256) of k>=512.
// Per step: A-frags loaded straight from global, 48 MFMA (32x32x16),
// cross-wave K-reduce via 24KB LDS, gates on waves 0/1, write-through h.

__global__ __launch_bounds__(256, 1) void lstm_persist(
    const ushort* __restrict__ xsb, const ushort* __restrict__ WT,
    const float* __restrict__ bias, const float* __restrict__ Wo,
    const float* __restrict__ bo, ushort* __restrict__ hbuf,
    uint* __restrict__ cnt, float* __restrict__ out) {

  __shared__ float sP[6 * 1024];   // partial exchange: 6 entries x 64 lanes x 16 f32

  const int tid = threadIdx.x;
  const int wg  = blockIdx.x;
  const int lane = tid & 63;
  const int wv = tid >> 6;         // wave id = K-slice
  const int c  = lane & 31;        // fragment col / A-row
  const int hi = lane >> 5;

  // ---- stationary weights into registers (once) ----
  const int gcol = (c >> 3) * 1024 + wg * 8 + (c & 7);
  uint4 Wr[24];
  {
    const ushort* wb = WT + gcol * 1536 + hi * 8;
#pragma unroll
    for (int kf = 0; kf < 24; ++kf) {
      int k = (kf < 8) ? (wv * 128 + kf * 16) : (512 + wv * 256 + (kf - 8) * 16);
      Wr[kf] = *(const uint4*)(wb + k);
    }
  }

  const float bc = bias[gcol];
  float cst[16];
#pragma unroll
  for (int r = 0; r < 16; ++r) cst[r] = 0.f;

  for (int t = 0; t < T_STEPS; ++t) {
    const ushort* __restrict__ hrd = hbuf + t * 65536;
    ushort* __restrict__ hwr = hbuf + (t + 1) * 65536;

    // ---- x-part A loads (independent of other WGs; in flight during spin) ----
    uint4 Ax[2][8];
    const ushort* xst = xsb + t * 32768;
#pragma unroll
    for (int m = 0; m < 2; ++m)
#pragma unroll
      for (int kf = 0; kf < 8; ++kf)
        Ax[m][kf] = *(const uint4*)(xst + (m * 32 + c) * 512 + wv * 128 + kf * 16 + hi * 8);

    // ---- wait for h_t (per-wave spin, lanes 0..7 cover the 8 stripes) ----
    if (t > 0) {
      if (lane < NCNT) {
        uint tgt = (uint)(CPW * t);
        while (__hip_atomic_load(cnt + lane * 32, __ATOMIC_RELAXED,
                                 __HIP_MEMORY_SCOPE_AGENT) < tgt)
          __builtin_amdgcn_s_sleep(1);
      }
      asm volatile("" ::: "memory");
    }

    // ---- h-part A loads ----
    uint4 Ah[2][16];
#pragma unroll
    for (int m = 0; m < 2; ++m)
#pragma unroll
      for (int kf = 0; kf < 16; ++kf)
        Ah[m][kf] = *(const uint4*)(hrd + (m * 32 + c) * 1024 + wv * 256 + kf * 16 + hi * 8);

    // ---- MFMA: 2 independent accumulator chains ----
    f32x16 acc0, acc1;
#pragma unroll
    for (int r = 0; r < 16; ++r) { acc0[r] = bc; acc1[r] = bc; }

#pragma unroll
    for (int kf = 0; kf < 8; ++kf) {
      F8 a0, a1, w; w.u4 = Wr[kf];
      a0.u4 = Ax[0][kf]; a1.u4 = Ax[1][kf];
      acc0 = __builtin_amdgcn_mfma_f32_32x32x16_bf16(a0.s, w.s, acc0, 0, 0, 0);
      acc1 = __builtin_amdgcn_mfma_f32_32x32x16_bf16(a1.s, w.s, acc1, 0, 0, 0);
    }
#pragma unroll
    for (int kf = 0; kf < 16; ++kf) {
      F8 a0, a1, w; w.u4 = Wr[8 + kf];
      a0.u4 = Ah[0][kf]; a1.u4 = Ah[1][kf];
      acc0 = __builtin_amdgcn_mfma_f32_32x32x16_bf16(a0.s, w.s, acc0, 0, 0, 0);
      acc1 = __builtin_amdgcn_mfma_f32_32x32x16_bf16(a1.s, w.s, acc1, 0, 0, 0);
    }

    // ---- cross-wave K reduction via LDS ----
    // entries: (0,m1)->0 (1,m0)->1 (2,m0)->2 (2,m1)->3 (3,m0)->4 (3,m1)->5
    {
      union PK { f32x16 v; f32x4 q[4]; } pa, pb;
      pa.v = acc0; pb.v = acc1;
      if (wv == 0) {
        float* p = sP + 0 * 1024 + lane * 16;
#pragma unroll
        for (int g = 0; g < 4; ++g) *(f32x4*)(p + g * 4) = pb.q[g];
      } else if (wv == 1) {
        float* p = sP + 1 * 1024 + lane * 16;
#pragma unroll
        for (int g = 0; g < 4; ++g) *(f32x4*)(p + g * 4) = pa.q[g];
      } else {
        float* p = sP + (wv * 2 - 2) * 1024 + lane * 16;
        float* p2 = sP + (wv * 2 - 1) * 1024 + lane * 16;
#pragma unroll
        for (int g = 0; g < 4; ++g) *(f32x4*)(p + g * 4) = pa.q[g];
#pragma unroll
        for (int g = 0; g < 4; ++g) *(f32x4*)(p2 + g * 4) = pb.q[g];
      }
    }
    __syncthreads();

    // ---- waves 0/1: finalize mfrag wv, gates, write-through h ----
    if (wv < 2) {
      union PK { f32x16 v; f32x4 q[4]; } s1, s2, s3;
      const int e1 = (wv == 0) ? 1 : 0;
      const int e2 = (wv == 0) ? 2 : 3;
      const int e3 = (wv == 0) ? 4 : 5;
      const float* p1 = sP + e1 * 1024 + lane * 16;
      const float* p2 = sP + e2 * 1024 + lane * 16;
      const float* p3 = sP + e3 * 1024 + lane * 16;
#pragma unroll
      for (int g = 0; g < 4; ++g) {
        s1.q[g] = *(const f32x4*)(p1 + g * 4);
        s2.q[g] = *(const f32x4*)(p2 + g * 4);
        s3.q[g] = *(const f32x4*)(p3 + g * 4);
      }
      f32x16 fin = ((wv == 0) ? acc0 : acc1) + s1.v + s2.v + s3.v;

#pragma unroll
      for (int r = 0; r < 16; ++r) {
        float own = fin[r];
        float vf = __shfl_xor(own, 8);
        float vg = __shfl_xor(own, 16);
        float vo = __shfl_xor(own, 24);
        float ig = 1.f / (1.f + __expf(-own));
        float fg = 1.f / (1.f + __expf(-vf));
        float gg = fmaxf(vg, 0.f);
        float og = 1.f / (1.f + __expf(-vo));
        float cn = fg * cst[r] + ig * gg;
        cst[r] = cn;
        ushort hv = f2bf(og * fmaxf(cn, 0.f));
        if (c < 8) {  // cols 0..7 hold gate i; lane stores unit wg*8+c
          int row = (r & 3) + 8 * (r >> 2) + 4 * hi + 32 * wv;
          asm volatile("global_store_short %0, %1, off sc0 sc1"
                       :: "v"(hwr + row * 1024 + wg * 8 + c), "v"((uint)hv) : "memory");
        }
      }
      asm volatile("s_waitcnt vmcnt(0)" ::: "memory");  // h at coherence point
    }
    __syncthreads();  // wave 1's stores drained before wave 0 signals
    if (tid == 0)
      __hip_atomic_fetch_add(cnt + (wg & 7) * 32, 1u, __ATOMIC_RELAXED,
                             __HIP_MEMORY_SCOPE_AGENT);
  }

  // ---- wait for final h, then out = h_T @ W_o + b_o ----
  if (lane < NCNT) {
    uint tgt = (uint)(CPW * T_STEPS);
    while (__hip_atomic_load(cnt + lane * 32, __ATOMIC_RELAXED,
                             __HIP_MEMORY_SCOPE_AGENT) < tgt)
      __builtin_amdgcn_s_sleep(1);
  }
  asm volatile("" ::: "memory");
  {
    int oidx = wg * 256 + tid;            // 0..32767
    int bb = oidx >> 9, oc = oidx & 511;
    const ushort* hr = hbuf + T_STEPS * 65536 + bb * 1024;
    float s = bo[oc];
#pragma unroll 4
    for (int k8 = 0; k8 < 128; ++k8) {
      uint4 hv = *(const uint4*)(hr + k8 * 8);
      const ushort* hp = (const ushort*)&hv;
#pragma unroll
      for (int j = 0; j < 8; ++j)
        s = fmaf(bf2f(hp[j]), Wo[(k8 * 8 + j) * 512 + oc], s);
    }
    out[oidx] = s;
  }
}

// ---------------- host launch ----------------

extern "C" void kernel_launch(void* const* d_in, const int* in_sizes, int n_in,
                              void* d_out, int out_size, void* d_ws, size_t ws_size,
                              hipStream_t stream) {
  (void)in_sizes; (void)n_in; (void)out_size; (void)ws_size;
  const float* xs  = (const float*)d_in[0];
  const float* Wih = (const float*)d_in[1];
  const float* Whh = (const float*)d_in[2];
  const float* b   = (const float*)d_in[3];
  const float* Wo  = (const float*)d_in[4];
  const float* bo  = (const float*)d_in[5];
  float* out = (float*)d_out;

  char* ws = (char*)d_ws;
  uint* cnt    = (uint*)ws;                                 // 8 stripe counters, 128B apart
  ushort* hbuf = (ushort*)(ws + 1024);                      // 129 x [64][1024] bf16
  ushort* xsb  = (ushort*)(ws + 1024 + 16908288);           // [128][64][512] bf16 (t-major)
  ushort* WT   = (ushort*)(ws + 1024 + 16908288 + 8388608); // [4096][1536] bf16

  // zero counters + h_0 every call (graph-safe)
  hipMemsetAsync(ws, 0, 1024 + 131072, stream);
  convert_xs_kernel<<<2048, 256, 0, stream>>>(xs, xsb);
  transpose_w_kernel<<<dim3(16, 128), 256, 0, stream>>>(Wih, WT, 0);
  transpose_w_kernel<<<dim3(32, 128), 256, 0, stream>>>(Whh, WT, 512);
  lstm_persist<<<NGRP, 256, 0, stream>>>(xsb, WT, b, Wo, bo, hbuf, cnt, out);
}

// Round 5
// 1111.480 us; speedup vs baseline: 2.3135x; 1.1309x over previous
//
#include <hip/hip_runtime.h>

typedef unsigned int uint;
typedef unsigned short ushort;
typedef __attribute__((ext_vector_type(8))) short short8;
typedef __attribute__((ext_vector_type(4))) float f32x4;
typedef __attribute__((ext_vector_type(16))) float f32x16;
typedef __attribute__((ext_vector_type(4))) uint uintx4;

#define T_STEPS 128
#define NGRP 128
#define NCNT 8            // stripe counters, 128B apart
#define CPW (NGRP/NCNT)   // adds per counter per step = 16

__device__ __forceinline__ ushort f2bf(float f) {
  union { float f; uint u; } v; v.f = f;
  uint r = v.u + 0x7fffu + ((v.u >> 16) & 1u);  // RNE
  return (ushort)(r >> 16);
}
__device__ __forceinline__ float bf2f(ushort u) {
  union { uint u; float f; } v; v.u = ((uint)u) << 16;
  return v.f;
}

union F8 { uint4 u4; short8 s; };

__device__ __forceinline__ void gload_lds16(const void* g, void* l) {
  __builtin_amdgcn_global_load_lds((const __attribute__((address_space(1))) void*)g,
                                   (__attribute__((address_space(3))) void*)l, 16, 0, 0);
}

// ---------------- init kernels ----------------

// xs f32 [64][128][512] -> xb bf16 blocked [128 t][64 blk][64 row][8]
__global__ void convert_xs_kernel(const float* __restrict__ xs, ushort* __restrict__ xb) {
  int idx = blockIdx.x * 256 + threadIdx.x;   // 524288 granules
  int t = idx >> 12;
  int b = (idx >> 6) & 63;
  int j = idx & 63;                           // k-block
  const float* src = xs + (b * 128 + t) * 512 + j * 8;
  float4 a = *(const float4*)src;
  float4 c = *(const float4*)(src + 4);
  union { ushort r[8]; uint4 v; } p;
  p.r[0] = f2bf(a.x); p.r[1] = f2bf(a.y); p.r[2] = f2bf(a.z); p.r[3] = f2bf(a.w);
  p.r[4] = f2bf(c.x); p.r[5] = f2bf(c.y); p.r[6] = f2bf(c.z); p.r[7] = f2bf(c.w);
  *(uint4*)(xb + t * 32768 + j * 512 + b * 8) = p.v;
}

// W f32 [K][4096] -> WT bf16 [4096][1536] at k-offset ko (W_ih: ko=0, W_hh: ko=512)
__global__ void transpose_w_kernel(const float* __restrict__ W, ushort* __restrict__ WT, int ko) {
  __shared__ ushort tile[32][33];
  int kt = blockIdx.x * 32, nt = blockIdx.y * 32;
  int tx = threadIdx.x & 31, ty = threadIdx.x >> 5;
#pragma unroll
  for (int i = 0; i < 4; ++i) {
    int kk = ty + i * 8;
    tile[kk][tx] = f2bf(W[(kt + kk) * 4096 + nt + tx]);
  }
  __syncthreads();
#pragma unroll
  for (int i = 0; i < 4; ++i) {
    int nn = ty + i * 8;
    WT[(nt + nn) * 1536 + ko + kt + tx] = tile[tx][nn];
  }
}

// ---------------- persistent LSTM kernel ----------------
// 128 WGs x 4 waves. WG owns 8 hidden units = 32 gate cols (i,f,g,o x 8).
// Weights in VGPRs. Wave wv owns K-slice; h staged via global_load_lds into
// the wave's private 32KB LDS region; partial reduce in each wave's own
// region (aliased after MFMAs); 4-way gate split; 1KB coalesced h store.

__global__ __launch_bounds__(256, 1) void lstm_persist(
    const ushort* __restrict__ xsb, const ushort* __restrict__ WT,
    const float* __restrict__ bias, const float* __restrict__ Wo,
    const float* __restrict__ bo, ushort* __restrict__ hbuf,
    uint* __restrict__ cnt, float* __restrict__ out) {

  __shared__ __align__(16) char ldsRaw[131072 + 2048];
  ushort* ldsH = (ushort*)ldsRaw;            // [128 blk][64 row][8] bf16 (per-wave 32 blk)
  float* sP = (float*)ldsRaw;                // per-wave region: [2 m][16 r][64 lane] f32 @ wv*32KB
  ushort* tr = (ushort*)(ldsRaw + 131072);   // [64 row][8 unit]

  const int tid = threadIdx.x;
  const int wg  = blockIdx.x;
  const int lane = tid & 63;
  const int wv = tid >> 6;         // wave id = K-slice
  const int c  = lane & 31;        // fragment col / A-row-in-half
  const int hi = lane >> 5;

  // ---- stationary weights into registers (once) ----
  const int gcol = (c >> 3) * 1024 + wg * 8 + (c & 7);
  uint4 Wr[24];
  {
    const ushort* wb = WT + gcol * 1536 + hi * 8;
#pragma unroll
    for (int kf = 0; kf < 24; ++kf) {
      int k = (kf < 8) ? (wv * 128 + kf * 16) : (512 + wv * 256 + (kf - 8) * 16);
      Wr[kf] = *(const uint4*)(wb + k);
    }
  }

  const float bc = bias[gcol];
  const int mval = wv >> 1;            // finalize: m-fragment
  const int rb = (wv & 1) * 8;         // finalize: acc-reg range [rb, rb+8)
  float cst[8];
#pragma unroll
  for (int r = 0; r < 8; ++r) cst[r] = 0.f;

  for (int t = 0; t < T_STEPS; ++t) {
    const ushort* __restrict__ hrd = hbuf + t * 65536;
    ushort* __restrict__ hwr = hbuf + (t + 1) * 65536;

    // ---- x-part: loads + MFMAs (independent of other WGs; fills wait window) ----
    f32x16 acc0 = {}, acc1 = {};
    {
      const ushort* xst = xsb + t * 32768;
#pragma unroll
      for (int kf = 0; kf < 8; ++kf) {
        int blk = wv * 16 + kf * 2 + hi;
        F8 a0, a1, w; w.u4 = Wr[kf];
        a0.u4 = *(const uint4*)(xst + blk * 512 + c * 8);
        a1.u4 = *(const uint4*)(xst + blk * 512 + (32 + c) * 8);
        acc0 = __builtin_amdgcn_mfma_f32_32x32x16_bf16(a0.s, w.s, acc0, 0, 0, 0);
        acc1 = __builtin_amdgcn_mfma_f32_32x32x16_bf16(a1.s, w.s, acc1, 0, 0, 0);
      }
    }

    // ---- wait for h_t ----
    if (t > 0) {
      if (lane < NCNT) {
        uint tgt = (uint)(CPW * t);
        while (__hip_atomic_load(cnt + lane * 32, __ATOMIC_RELAXED,
                                 __HIP_MEMORY_SCOPE_AGENT) < tgt)
          __builtin_amdgcn_s_sleep(1);
      }
      asm volatile("" ::: "memory");
    }

    // ---- h-part: async global->LDS (32 x 1KB blocks, wave-private region) ----
#pragma unroll
    for (int i = 0; i < 32; ++i) {
      int blk = wv * 32 + i;
      gload_lds16(hrd + blk * 512 + lane * 8, ldsH + blk * 512);
    }
    asm volatile("s_waitcnt vmcnt(0)" ::: "memory");

#pragma unroll
    for (int kf = 0; kf < 16; ++kf) {
      int blk = wv * 32 + kf * 2 + hi;
      F8 a0, a1, w; w.u4 = Wr[8 + kf];
      a0.u4 = *(const uint4*)(ldsH + blk * 512 + c * 8);
      a1.u4 = *(const uint4*)(ldsH + blk * 512 + (32 + c) * 8);
      acc0 = __builtin_amdgcn_mfma_f32_32x32x16_bf16(a0.s, w.s, acc0, 0, 0, 0);
      acc1 = __builtin_amdgcn_mfma_f32_32x32x16_bf16(a1.s, w.s, acc1, 0, 0, 0);
    }

    // ---- partial write into wave's OWN region (its h blocks are consumed) ----
    {
      float* p = sP + wv * 8192 + lane;  // [m][r][lane]
#pragma unroll
      for (int r = 0; r < 16; ++r) p[r * 64] = acc0[r];
#pragma unroll
      for (int r = 0; r < 16; ++r) p[1024 + r * 64] = acc1[r];
    }
    __syncthreads();

    // ---- reduce quarter (m = mval, regs [rb, rb+8)), gates, h -> tr ----
#pragma unroll
    for (int rr = 0; rr < 8; ++rr) {
      int r = rb + rr;
      int o = mval * 1024 + r * 64 + lane;
      float own = sP[o] + sP[8192 + o] + sP[16384 + o] + sP[24576 + o] + bc;
      float vf = __shfl_xor(own, 8);
      float vg = __shfl_xor(own, 16);
      float vo = __shfl_xor(own, 24);
      float ig = 1.f / (1.f + __expf(-own));
      float fg = 1.f / (1.f + __expf(-vf));
      float gg = fmaxf(vg, 0.f);
      float og = 1.f / (1.f + __expf(-vo));
      float cn = fg * cst[rr] + ig * gg;
      cst[rr] = cn;
      ushort hv = f2bf(og * fmaxf(cn, 0.f));
      if (c < 8) {  // i-gate cols hold the unit's h value
        int row = (r & 3) + 8 * (r >> 2) + 4 * hi + 32 * mval;
        tr[row * 8 + c] = hv;
      }
    }
    __syncthreads();

    // ---- wave 0: one coalesced 1KB write-through store + signal ----
    if (wv == 0) {
      uintx4 hq = *(const uintx4*)(tr + lane * 8);
      asm volatile("global_store_dwordx4 %0, %1, off sc0 sc1"
                   :: "v"(hwr + wg * 512 + lane * 8), "v"(hq) : "memory");
      asm volatile("s_waitcnt vmcnt(0)" ::: "memory");
      if (lane == 0)
        __hip_atomic_fetch_add(cnt + (wg & 7) * 32, 1u, __ATOMIC_RELAXED,
                               __HIP_MEMORY_SCOPE_AGENT);
    }
  }

  // ---- wait for final h, then out = h_T @ W_o + b_o ----
  if (lane < NCNT) {
    uint tgt = (uint)(CPW * T_STEPS);
    while (__hip_atomic_load(cnt + lane * 32, __ATOMIC_RELAXED,
                             __HIP_MEMORY_SCOPE_AGENT) < tgt)
      __builtin_amdgcn_s_sleep(1);
  }
  asm volatile("" ::: "memory");
  __syncthreads();
  {
    int oidx = wg * 256 + tid;            // 0..32767
    int bb = oidx >> 9, oc = oidx & 511;
    const ushort* hr = hbuf + T_STEPS * 65536;
    float s = bo[oc];
#pragma unroll 4
    for (int k8 = 0; k8 < 128; ++k8) {
      uint4 hv = *(const uint4*)(hr + k8 * 512 + bb * 8);
      const ushort* hp = (const ushort*)&hv;
#pragma unroll
      for (int j = 0; j < 8; ++j)
        s = fmaf(bf2f(hp[j]), Wo[(k8 * 8 + j) * 512 + oc], s);
    }
    out[oidx] = s;
  }
}

// ---------------- host launch ----------------

extern "C" void kernel_launch(void* const* d_in, const int* in_sizes, int n_in,
                              void* d_out, int out_size, void* d_ws, size_t ws_size,
                              hipStream_t stream) {
  (void)in_sizes; (void)n_in; (void)out_size; (void)ws_size;
  const float* xs  = (const float*)d_in[0];
  const float* Wih = (const float*)d_in[1];
  const float* Whh = (const float*)d_in[2];
  const float* b   = (const float*)d_in[3];
  const float* Wo  = (const float*)d_in[4];
  const float* bo  = (const float*)d_in[5];
  float* out = (float*)d_out;

  char* ws = (char*)d_ws;
  uint* cnt    = (uint*)ws;                                 // 8 stripe counters, 128B apart
  ushort* hbuf = (ushort*)(ws + 1024);                      // 129 x [128 wg][64 row][8] bf16
  ushort* xsb  = (ushort*)(ws + 1024 + 16908288);           // [128 t][64 blk][64 row][8] bf16
  ushort* WT   = (ushort*)(ws + 1024 + 16908288 + 8388608); // [4096][1536] bf16

  // zero counters + h_0 every call (graph-safe)
  hipMemsetAsync(ws, 0, 1024 + 131072, stream);
  convert_xs_kernel<<<2048, 256, 0, stream>>>(xs, xsb);
  transpose_w_kernel<<<dim3(16, 128), 256, 0, stream>>>(Wih, WT, 0);
  transpose_w_kernel<<<dim3(32, 128), 256, 0, stream>>>(Whh, WT, 512);
  lstm_persist<<<NGRP, 256, 0, stream>>>(xsb, WT, b, Wo, bo, hbuf, cnt, out);
}

// Round 6
// 799.701 us; speedup vs baseline: 3.2155x; 1.3899x over previous
//
#include <hip/hip_runtime.h>

typedef unsigned int uint;
typedef unsigned short ushort;
typedef __attribute__((ext_vector_type(8))) short short8;
typedef __attribute__((ext_vector_type(4))) float f32x4;
typedef __attribute__((ext_vector_type(16))) float f32x16;
typedef __attribute__((ext_vector_type(4))) uint uintx4;

#define T_STEPS 128
#define NGRP 128
#define NCNT 8            // stripe counters, 128B apart
#define CPW (NGRP/NCNT)   // adds per counter per step = 16

__device__ __forceinline__ ushort f2bf(float f) {
  union { float f; uint u; } v; v.f = f;
  uint r = v.u + 0x7fffu + ((v.u >> 16) & 1u);  // RNE
  return (ushort)(r >> 16);
}
__device__ __forceinline__ float bf2f(ushort u) {
  union { uint u; float f; } v; v.u = ((uint)u) << 16;
  return v.f;
}

union F8 { uint4 u4; short8 s; };

__device__ __forceinline__ void gload_lds16(const void* g, void* l) {
  __builtin_amdgcn_global_load_lds((const __attribute__((address_space(1))) void*)g,
                                   (__attribute__((address_space(3))) void*)l, 16, 0, 0);
}

// ---------------- init kernels ----------------

// xs f32 [64][128][512] -> xb bf16 blocked [128 t][64 blk][64 row][8]
__global__ void convert_xs_kernel(const float* __restrict__ xs, ushort* __restrict__ xb) {
  int idx = blockIdx.x * 256 + threadIdx.x;   // 524288 granules
  int t = idx >> 12;
  int b = (idx >> 6) & 63;
  int j = idx & 63;                           // k-block
  const float* src = xs + (b * 128 + t) * 512 + j * 8;
  float4 a = *(const float4*)src;
  float4 c = *(const float4*)(src + 4);
  union { ushort r[8]; uint4 v; } p;
  p.r[0] = f2bf(a.x); p.r[1] = f2bf(a.y); p.r[2] = f2bf(a.z); p.r[3] = f2bf(a.w);
  p.r[4] = f2bf(c.x); p.r[5] = f2bf(c.y); p.r[6] = f2bf(c.z); p.r[7] = f2bf(c.w);
  *(uint4*)(xb + t * 32768 + j * 512 + b * 8) = p.v;
}

// W f32 [K][4096] -> WT bf16 [4096][1536] at k-offset ko (W_ih: ko=0, W_hh: ko=512)
__global__ void transpose_w_kernel(const float* __restrict__ W, ushort* __restrict__ WT, int ko) {
  __shared__ ushort tile[32][33];
  int kt = blockIdx.x * 32, nt = blockIdx.y * 32;
  int tx = threadIdx.x & 31, ty = threadIdx.x >> 5;
#pragma unroll
  for (int i = 0; i < 4; ++i) {
    int kk = ty + i * 8;
    tile[kk][tx] = f2bf(W[(kt + kk) * 4096 + nt + tx]);
  }
  __syncthreads();
#pragma unroll
  for (int i = 0; i < 4; ++i) {
    int nn = ty + i * 8;
    WT[(nt + nn) * 1536 + ko + kt + tx] = tile[tx][nn];
  }
}

// ---------------- persistent LSTM kernel ----------------
// 128 WGs x 4 waves. WG owns 8 hidden units = 32 gate cols (i,f,g,o x 8).
// Weights in VGPRs. Wave wv owns K-slice; h staged via global_load_lds into
// the wave's private 32KB LDS region; partial reduce aliased in the same
// region; 4-way gate split; 1KB coalesced AGENT-scope (sc1) h store;
// wave-0-only polling with s_sleep backoff; x-MFMAs fill the h-fetch shadow.

__global__ __launch_bounds__(256, 1) void lstm_persist(
    const ushort* __restrict__ xsb, const ushort* __restrict__ WT,
    const float* __restrict__ bias, const float* __restrict__ Wo,
    const float* __restrict__ bo, ushort* __restrict__ hbuf,
    uint* __restrict__ cnt, float* __restrict__ out) {

  __shared__ __align__(16) char ldsRaw[131072 + 2048];
  ushort* ldsH = (ushort*)ldsRaw;            // [128 blk][64 row][8] bf16 (per-wave 32 blk)
  float* sP = (float*)ldsRaw;                // per-wave region: [2 m][16 r][64 lane] f32 @ wv*32KB
  ushort* tr = (ushort*)(ldsRaw + 131072);   // [64 row][8 unit]

  const int tid = threadIdx.x;
  const int wg  = blockIdx.x;
  const int lane = tid & 63;
  const int wv = tid >> 6;         // wave id = K-slice
  const int c  = lane & 31;        // fragment col / A-row-in-half
  const int hi = lane >> 5;

  // ---- stationary weights into registers (once) ----
  const int gcol = (c >> 3) * 1024 + wg * 8 + (c & 7);
  uint4 Wr[24];
  {
    const ushort* wb = WT + gcol * 1536 + hi * 8;
#pragma unroll
    for (int kf = 0; kf < 24; ++kf) {
      int k = (kf < 8) ? (wv * 128 + kf * 16) : (512 + wv * 256 + (kf - 8) * 16);
      Wr[kf] = *(const uint4*)(wb + k);
    }
  }

  const float bc = bias[gcol];
  const int mval = wv >> 1;            // finalize: m-fragment
  const int rb = (wv & 1) * 8;         // finalize: acc-reg range [rb, rb+8)
  float cst[8];
#pragma unroll
  for (int r = 0; r < 8; ++r) cst[r] = 0.f;

  for (int t = 0; t < T_STEPS; ++t) {
    const ushort* __restrict__ hrd = hbuf + t * 65536;
    ushort* __restrict__ hwr = hbuf + (t + 1) * 65536;

    // ---- x-part A loads issued BEFORE the spin (L2/L3 fetch overlaps wait) ----
    uint4 Ax[16];
    {
      const ushort* xst = xsb + t * 32768;
#pragma unroll
      for (int kf = 0; kf < 8; ++kf) {
        int blk = wv * 16 + kf * 2 + hi;
        Ax[kf]     = *(const uint4*)(xst + blk * 512 + c * 8);
        Ax[8 + kf] = *(const uint4*)(xst + blk * 512 + (32 + c) * 8);
      }
    }

    // ---- wait for h_t: ONLY wave 0 polls; others sleep at the barrier ----
    if (t > 0) {
      if (wv == 0 && lane < NCNT) {
        uint tgt = (uint)(CPW * t);
        while (__hip_atomic_load(cnt + lane * 32, __ATOMIC_RELAXED,
                                 __HIP_MEMORY_SCOPE_AGENT) < tgt)
          __builtin_amdgcn_s_sleep(2);
      }
      __syncthreads();
    }

    // ---- h-part: async global->LDS issued FIRST (latency hidden by x-MFMAs) ----
#pragma unroll
    for (int i = 0; i < 32; ++i) {
      int blk = wv * 32 + i;
      gload_lds16(hrd + blk * 512 + lane * 8, ldsH + blk * 512);
    }

    // ---- x-part MFMAs (fill the h-fetch shadow) ----
    f32x16 acc0 = {}, acc1 = {};
#pragma unroll
    for (int kf = 0; kf < 8; ++kf) {
      F8 a0, a1, w; w.u4 = Wr[kf];
      a0.u4 = Ax[kf]; a1.u4 = Ax[8 + kf];
      acc0 = __builtin_amdgcn_mfma_f32_32x32x16_bf16(a0.s, w.s, acc0, 0, 0, 0);
      acc1 = __builtin_amdgcn_mfma_f32_32x32x16_bf16(a1.s, w.s, acc1, 0, 0, 0);
    }
    asm volatile("s_waitcnt vmcnt(0)" ::: "memory");

#pragma unroll
    for (int kf = 0; kf < 16; ++kf) {
      int blk = wv * 32 + kf * 2 + hi;
      F8 a0, a1, w; w.u4 = Wr[8 + kf];
      a0.u4 = *(const uint4*)(ldsH + blk * 512 + c * 8);
      a1.u4 = *(const uint4*)(ldsH + blk * 512 + (32 + c) * 8);
      acc0 = __builtin_amdgcn_mfma_f32_32x32x16_bf16(a0.s, w.s, acc0, 0, 0, 0);
      acc1 = __builtin_amdgcn_mfma_f32_32x32x16_bf16(a1.s, w.s, acc1, 0, 0, 0);
    }

    // ---- partial write into wave's OWN region (its h blocks are consumed) ----
    {
      float* p = sP + wv * 8192 + lane;  // [m][r][lane]
#pragma unroll
      for (int r = 0; r < 16; ++r) p[r * 64] = acc0[r];
#pragma unroll
      for (int r = 0; r < 16; ++r) p[1024 + r * 64] = acc1[r];
    }
    __syncthreads();

    // ---- reduce quarter (m = mval, regs [rb, rb+8)), gates, h -> tr ----
#pragma unroll
    for (int rr = 0; rr < 8; ++rr) {
      int r = rb + rr;
      int o = mval * 1024 + r * 64 + lane;
      float own = sP[o] + sP[8192 + o] + sP[16384 + o] + sP[24576 + o] + bc;
      float vf = __shfl_xor(own, 8);
      float vg = __shfl_xor(own, 16);
      float vo = __shfl_xor(own, 24);
      float ig = 1.f / (1.f + __expf(-own));
      float fg = 1.f / (1.f + __expf(-vf));
      float gg = fmaxf(vg, 0.f);
      float og = 1.f / (1.f + __expf(-vo));
      float cn = fg * cst[rr] + ig * gg;
      cst[rr] = cn;
      ushort hv = f2bf(og * fmaxf(cn, 0.f));
      if (c < 8) {  // i-gate cols hold the unit's h value
        int row = (r & 3) + 8 * (r >> 2) + 4 * hi + 32 * mval;
        tr[row * 8 + c] = hv;
      }
    }
    __syncthreads();

    // ---- wave 0: one coalesced 1KB AGENT-scope store + signal ----
    if (wv == 0) {
      uintx4 hq = *(const uintx4*)(tr + lane * 8);
      asm volatile("global_store_dwordx4 %0, %1, off sc1"
                   :: "v"(hwr + wg * 512 + lane * 8), "v"(hq) : "memory");
      asm volatile("s_waitcnt vmcnt(0)" ::: "memory");  // ack at MALL, not HBM
      if (lane == 0)
        __hip_atomic_fetch_add(cnt + (wg & 7) * 32, 1u, __ATOMIC_RELAXED,
                               __HIP_MEMORY_SCOPE_AGENT);
    }
  }

  // ---- wait for final h, then out = h_T @ W_o + b_o ----
  if (wv == 0 && lane < NCNT) {
    uint tgt = (uint)(CPW * T_STEPS);
    while (__hip_atomic_load(cnt + lane * 32, __ATOMIC_RELAXED,
                             __HIP_MEMORY_SCOPE_AGENT) < tgt)
      __builtin_amdgcn_s_sleep(2);
  }
  __syncthreads();
  {
    int oidx = wg * 256 + tid;            // 0..32767
    int bb = oidx >> 9, oc = oidx & 511;
    const ushort* hr = hbuf + T_STEPS * 65536;
    float s = bo[oc];
#pragma unroll 4
    for (int k8 = 0; k8 < 128; ++k8) {
      uint4 hv = *(const uint4*)(hr + k8 * 512 + bb * 8);
      const ushort* hp = (const ushort*)&hv;
#pragma unroll
      for (int j = 0; j < 8; ++j)
        s = fmaf(bf2f(hp[j]), Wo[(k8 * 8 + j) * 512 + oc], s);
    }
    out[oidx] = s;
  }
}

// ---------------- host launch ----------------

extern "C" void kernel_launch(void* const* d_in, const int* in_sizes, int n_in,
                              void* d_out, int out_size, void* d_ws, size_t ws_size,
                              hipStream_t stream) {
  (void)in_sizes; (void)n_in; (void)out_size; (void)ws_size;
  const float* xs  = (const float*)d_in[0];
  const float* Wih = (const float*)d_in[1];
  const float* Whh = (const float*)d_in[2];
  const float* b   = (const float*)d_in[3];
  const float* Wo  = (const float*)d_in[4];
  const float* bo  = (const float*)d_in[5];
  float* out = (float*)d_out;

  char* ws = (char*)d_ws;
  uint* cnt    = (uint*)ws;                                 // 8 stripe counters, 128B apart
  ushort* hbuf = (ushort*)(ws + 1024);                      // 129 x [128 wg][64 row][8] bf16
  ushort* xsb  = (ushort*)(ws + 1024 + 16908288);           // [128 t][64 blk][64 row][8] bf16
  ushort* WT   = (ushort*)(ws + 1024 + 16908288 + 8388608); // [4096][1536] bf16

  // zero counters + h_0 every call (graph-safe)
  hipMemsetAsync(ws, 0, 1024 + 131072, stream);
  convert_xs_kernel<<<2048, 256, 0, stream>>>(xs, xsb);
  transpose_w_kernel<<<dim3(16, 128), 256, 0, stream>>>(Wih, WT, 0);
  transpose_w_kernel<<<dim3(32, 128), 256, 0, stream>>>(Whh, WT, 512);
  lstm_persist<<<NGRP, 256, 0, stream>>>(xsb, WT, b, Wo, bo, hbuf, cnt, out);
}

// Round 7
// 480.266 us; speedup vs baseline: 5.3542x; 1.6651x over previous
//
#include <hip/hip_runtime.h>

typedef unsigned int uint;
typedef unsigned short ushort;
typedef __attribute__((ext_vector_type(8))) short short8;
typedef __attribute__((ext_vector_type(16))) float f32x16;
typedef __attribute__((ext_vector_type(4))) uint uintx4;

#define T_STEPS 128
#define NGRP 128          // 2 replicas x 64 WGs
#define NCNT 8            // stripe counters per replica, 128B apart
#define CPW 8             // adds per counter per step (64 WGs / 8 stripes)

__device__ __forceinline__ ushort f2bf(float f) {
  union { float f; uint u; } v; v.f = f;
  uint r = v.u + 0x7fffu + ((v.u >> 16) & 1u);  // RNE
  return (ushort)(r >> 16);
}
__device__ __forceinline__ float bf2f(ushort u) {
  union { uint u; float f; } v; v.u = ((uint)u) << 16;
  return v.f;
}

union F8 { uint4 u4; short8 s; };

// ---------------- init kernels ----------------

// xs f32 [64][128][512] -> xb bf16 blocked [128 t][64 kblk][64 row][8]
__global__ void convert_xs_kernel(const float* __restrict__ xs, ushort* __restrict__ xb) {
  int idx = blockIdx.x * 256 + threadIdx.x;   // 524288 granules
  int t = idx >> 12;
  int b = (idx >> 6) & 63;
  int j = idx & 63;                           // k-block
  const float* src = xs + (b * 128 + t) * 512 + j * 8;
  float4 a = *(const float4*)src;
  float4 c = *(const float4*)(src + 4);
  union { ushort r[8]; uint4 v; } p;
  p.r[0] = f2bf(a.x); p.r[1] = f2bf(a.y); p.r[2] = f2bf(a.z); p.r[3] = f2bf(a.w);
  p.r[4] = f2bf(c.x); p.r[5] = f2bf(c.y); p.r[6] = f2bf(c.z); p.r[7] = f2bf(c.w);
  *(uint4*)(xb + t * 32768 + j * 512 + b * 8) = p.v;
}

// W f32 [K][4096] -> WT bf16 [4096][1536] at k-offset ko (W_ih: ko=0, W_hh: ko=512)
__global__ void transpose_w_kernel(const float* __restrict__ W, ushort* __restrict__ WT, int ko) {
  __shared__ ushort tile[32][33];
  int kt = blockIdx.x * 32, nt = blockIdx.y * 32;
  int tx = threadIdx.x & 31, ty = threadIdx.x >> 5;
#pragma unroll
  for (int i = 0; i < 4; ++i) {
    int kk = ty + i * 8;
    tile[kk][tx] = f2bf(W[(kt + kk) * 4096 + nt + tx]);
  }
  __syncthreads();
#pragma unroll
  for (int i = 0; i < 4; ++i) {
    int nn = ty + i * 8;
    WT[(nt + nn) * 1536 + ko + kt + tx] = tile[tx][nn];
  }
}

// ---------------- persistent LSTM kernel ----------------
// 2 replicas (batch rows 0-31 / 32-63) x 64 WGs x 512 threads (8 waves).
// WG owns 16 units = 64 gate cols (2 N-frags: [i,f] and [g,o]); M=32 rows.
// K=1536 split 8 ways across waves (x:64k, h:128k each); weights in VGPRs.
// h per step: [64 blk][32 row][16 unit] per replica -> consumer loads are
// 8 fully-coalesced 1KB global loads straight into A-fragments (no LDS).
// 8-way K-reduce via conflict-free sP (bank=lane); 1KB sc1 store + signal.

__global__ __launch_bounds__(512, 1) void lstm_persist(
    const ushort* __restrict__ xsb, const ushort* __restrict__ WT,
    const float* __restrict__ bias, const float* __restrict__ Wo,
    const float* __restrict__ bo, ushort* __restrict__ hbuf,
    uint* __restrict__ cnt, float* __restrict__ out) {

  __shared__ float sP[8 * 2 * 16 * 64];   // [wv][nf][r][lane] 64KB
  __shared__ ushort tr[512];              // [32 row][16 unit]

  const int tid = threadIdx.x;
  const int wg  = blockIdx.x;
  const int lane = tid & 63;
  const int wv = tid >> 6;         // wave id = K-slice (0..7)
  const int c  = lane & 31;        // fragment col / A-row
  const int hi = lane >> 5;
  const int rep = wg >> 6;         // replica: batch rows rep*32..rep*32+31
  const int wgu = wg & 63;         // unit-block: units wgu*16..wgu*16+15

  // ---- stationary weights (once): 2 N-frags x (4 x-kfrags + 8 h-kfrags) ----
  const int gc0 = ((c >> 4)) * 1024 + wgu * 16 + (c & 15);        // gates i/f
  const int gc1 = (2 + (c >> 4)) * 1024 + wgu * 16 + (c & 15);    // gates g/o
  uint4 Wx[4][2], Wh[8][2];
#pragma unroll
  for (int kf = 0; kf < 4; ++kf) {
    int k = wv * 64 + kf * 16 + hi * 8;
    Wx[kf][0] = *(const uint4*)(WT + gc0 * 1536 + k);
    Wx[kf][1] = *(const uint4*)(WT + gc1 * 1536 + k);
  }
#pragma unroll
  for (int i = 0; i < 8; ++i) {
    int k = 512 + (wv * 8 + i) * 16 + hi * 8;
    Wh[i][0] = *(const uint4*)(WT + gc0 * 1536 + k);
    Wh[i][1] = *(const uint4*)(WT + gc1 * 1536 + k);
  }

  const float bc0 = bias[gc0];
  const float bc1 = bias[gc1];
  const int r0f = wv * 2;          // finalize: this wave handles regs r0f, r0f+1
  float cst[2] = {0.f, 0.f};

  for (int t = 0; t < T_STEPS; ++t) {
    const ushort* __restrict__ hrd = hbuf + t * 65536 + rep * 32768;
    ushort* __restrict__ hwr = hbuf + (t + 1) * 65536 + rep * 32768;

    // ---- x-part A loads issued BEFORE the spin ----
    uint4 Ax[4];
    {
      const ushort* xst = xsb + t * 32768 + rep * 256 + c * 8;
#pragma unroll
      for (int kf = 0; kf < 4; ++kf)
        Ax[kf] = *(const uint4*)(xst + (wv * 8 + kf * 2 + hi) * 512);
    }

    // ---- wait for h_t: wave 0 polls replica's 8 stripes ----
    if (t > 0) {
      if (wv == 0 && lane < NCNT) {
        uint tgt = (uint)(CPW * t);
        while (__hip_atomic_load(cnt + (rep * 8 + lane) * 32, __ATOMIC_RELAXED,
                                 __HIP_MEMORY_SCOPE_AGENT) < tgt)
          __builtin_amdgcn_s_sleep(2);
      }
      __syncthreads();
    }

    // ---- h-part A loads: 8 coalesced 1KB loads straight to registers ----
    uint4 Ah[8];
    {
      const ushort* hb = hrd + (wv * 8) * 512 + c * 16 + hi * 8;
#pragma unroll
      for (int i = 0; i < 8; ++i)
        Ah[i] = *(const uint4*)(hb + i * 512);
    }

    // ---- MFMA: 24 x 32x32x16, two independent chains ----
    f32x16 acc0 = {}, acc1 = {};
#pragma unroll
    for (int kf = 0; kf < 4; ++kf) {
      F8 a, w0, w1; a.u4 = Ax[kf]; w0.u4 = Wx[kf][0]; w1.u4 = Wx[kf][1];
      acc0 = __builtin_amdgcn_mfma_f32_32x32x16_bf16(a.s, w0.s, acc0, 0, 0, 0);
      acc1 = __builtin_amdgcn_mfma_f32_32x32x16_bf16(a.s, w1.s, acc1, 0, 0, 0);
    }
#pragma unroll
    for (int i = 0; i < 8; ++i) {
      F8 a, w0, w1; a.u4 = Ah[i]; w0.u4 = Wh[i][0]; w1.u4 = Wh[i][1];
      acc0 = __builtin_amdgcn_mfma_f32_32x32x16_bf16(a.s, w0.s, acc0, 0, 0, 0);
      acc1 = __builtin_amdgcn_mfma_f32_32x32x16_bf16(a.s, w1.s, acc1, 0, 0, 0);
    }

    // ---- partials to LDS (bank = lane: conflict-free) ----
    {
      float* p = sP + wv * 2048 + lane;
#pragma unroll
      for (int r = 0; r < 16; ++r) p[r * 64] = acc0[r];
#pragma unroll
      for (int r = 0; r < 16; ++r) p[1024 + r * 64] = acc1[r];
    }
    __syncthreads();

    // ---- finalize: wave wv reduces regs r0f..r0f+1 over 8 K-slices ----
#pragma unroll
    for (int s = 0; s < 2; ++s) {
      int r = r0f + s;
      int o = r * 64 + lane;
      float f0 = bc0, f1 = bc1;
#pragma unroll
      for (int w = 0; w < 8; ++w) {
        f0 += sP[w * 2048 + o];
        f1 += sP[w * 2048 + 1024 + o];
      }
      // unit u = c&15: i = f0@u, f = f0@(u+16), g = f1@u, o = f1@(u+16)
      float ff = __shfl_xor(f0, 16);
      float oo = __shfl_xor(f1, 16);
      float ig = 1.f / (1.f + __expf(-f0));
      float fg = 1.f / (1.f + __expf(-ff));
      float gg = fmaxf(f1, 0.f);
      float og = 1.f / (1.f + __expf(-oo));
      float cn = fg * cst[s] + ig * gg;
      cst[s] = cn;
      ushort hv = f2bf(og * fmaxf(cn, 0.f));
      if (c < 16) {
        int row = (r & 3) + 8 * (r >> 2) + 4 * hi;   // verified 32x32 C layout
        tr[row * 16 + c] = hv;
      }
    }
    __syncthreads();

    // ---- wave 0: one coalesced 1KB agent-scope store + signal ----
    if (wv == 0) {
      uintx4 hq = *(const uintx4*)((const ushort*)tr + lane * 8);
      asm volatile("global_store_dwordx4 %0, %1, off sc1"
                   :: "v"(hwr + wgu * 512 + lane * 8), "v"(hq) : "memory");
      asm volatile("s_waitcnt vmcnt(0)" ::: "memory");
      if (lane == 0)
        __hip_atomic_fetch_add(cnt + (rep * 8 + (wgu & 7)) * 32, 1u,
                               __ATOMIC_RELAXED, __HIP_MEMORY_SCOPE_AGENT);
    }
  }

  // ---- wait for BOTH replicas' final h, then out = h_T @ W_o + b_o ----
  if (wv == 0 && lane < 16) {
    uint tgt = (uint)(CPW * T_STEPS);
    while (__hip_atomic_load(cnt + lane * 32, __ATOMIC_RELAXED,
                             __HIP_MEMORY_SCOPE_AGENT) < tgt)
      __builtin_amdgcn_s_sleep(2);
  }
  __syncthreads();
  if (tid < 256) {
    int oidx = wg * 256 + tid;            // 0..32767
    int b = oidx >> 9, oc = oidx & 511;
    int rep2 = b >> 5, row = b & 31;
    const ushort* hf = hbuf + T_STEPS * 65536 + rep2 * 32768 + row * 16;
    float s = bo[oc];
#pragma unroll 2
    for (int w = 0; w < 64; ++w) {
      uint4 h0 = *(const uint4*)(hf + w * 512);
      uint4 h1 = *(const uint4*)(hf + w * 512 + 8);
      const ushort* p0 = (const ushort*)&h0;
      const ushort* p1 = (const ushort*)&h1;
#pragma unroll
      for (int j = 0; j < 8; ++j)
        s = fmaf(bf2f(p0[j]), Wo[(w * 16 + j) * 512 + oc], s);
#pragma unroll
      for (int j = 0; j < 8; ++j)
        s = fmaf(bf2f(p1[j]), Wo[(w * 16 + 8 + j) * 512 + oc], s);
    }
    out[oidx] = s;
  }
}

// ---------------- host launch ----------------

extern "C" void kernel_launch(void* const* d_in, const int* in_sizes, int n_in,
                              void* d_out, int out_size, void* d_ws, size_t ws_size,
                              hipStream_t stream) {
  (void)in_sizes; (void)n_in; (void)out_size; (void)ws_size;
  const float* xs  = (const float*)d_in[0];
  const float* Wih = (const float*)d_in[1];
  const float* Whh = (const float*)d_in[2];
  const float* b   = (const float*)d_in[3];
  const float* Wo  = (const float*)d_in[4];
  const float* bo  = (const float*)d_in[5];
  float* out = (float*)d_out;

  char* ws = (char*)d_ws;
  uint* cnt    = (uint*)ws;                                 // 16 stripe counters, 128B apart
  ushort* hbuf = (ushort*)(ws + 4096);                      // 129 x [2 rep][64 blk][32 row][16] bf16
  ushort* xsb  = (ushort*)(ws + 4096 + 16908288);           // [128 t][64 kblk][64 row][8] bf16
  ushort* WT   = (ushort*)(ws + 4096 + 16908288 + 8388608); // [4096][1536] bf16

  // zero counters + h_0 every call (graph-safe)
  hipMemsetAsync(ws, 0, 4096 + 131072, stream);
  convert_xs_kernel<<<2048, 256, 0, stream>>>(xs, xsb);
  transpose_w_kernel<<<dim3(16, 128), 256, 0, stream>>>(Wih, WT, 0);
  transpose_w_kernel<<<dim3(32, 128), 256, 0, stream>>>(Whh, WT, 512);
  lstm_persist<<<NGRP, 512, 0, stream>>>(xsb, WT, b, Wo, bo, hbuf, cnt, out);
}